// Round 4
// baseline (109682.068 us; speedup 1.0000x reference)
//
#include <hip/hip_runtime.h>
#include <math.h>

// EncoderDecoder LSTM seq2seq, f32 throughout (argmax feedback requires
// reference-matching precision; no fp32 MFMA on CDNA4).
//
// v3: software-pipelined staging (issue chunk ch+1 globals before compute of
// ch), 2j x 4b register tile (8 acc, 32 FMA per 6 conflict-free ds_read_b128),
// quad-XOR LDS swizzles, argmax fused into decoder cell0 (449 dispatches).

#define BB   32
#define SEQ  128
#define HID  1024
#define NV   32000
#define TDEC 64
#define NPRT 500

__device__ __forceinline__ float sgm(float x) { return 1.0f / (1.0f + expf(-x)); }
__device__ __forceinline__ float dot4(float4 a, float4 b) {
    return a.x*b.x + a.y*b.y + a.z*b.z + a.w*b.w;
}

// ---------------------------------------------------------------------------
// Fused LSTM cell. grid = 512 blocks; block owns 2 hidden cols (j0, j0+1)
// x 4 gates = 8 gate-rows; block = 512 thr.
// Thread map: bg = tid&7 (b-quad), jg = (tid>>3)&3 (row pair), ks = tid>>5
// (16-way K split; per 256-chunk each ks owns 16 contiguous k).
// Per k-quad: 4 a-reads + 2 w-reads (b128, XOR-swizzled conflict-free),
// 32 FMA into 8 acc. Staging pipelined: chunk ch+1 global->regs issued
// before compute(ch), regs->LDS after.
// Optional fused argmax over logits partials (decoder feedback token).
// ---------------------------------------------------------------------------
template <int XK>
__global__ void __launch_bounds__(512) lstm_cell(
    const float* __restrict__ xdir,   // [BB][XK] or nullptr
    const float* __restrict__ emb,    // [V][XK] or nullptr
    const int*   __restrict__ idx, int idx_stride, int idx_off,
    const int*   __restrict__ tok,    // token array path (decoder t=0)
    const float* __restrict__ pval,   // argmax-fused path (decoder t>0)
    const int*   __restrict__ pidx,
    const float* __restrict__ Wih,    // [4H][XK]
    const float* __restrict__ Whh,    // [4H][H]
    const float* __restrict__ bias,   // [4H]
    const float* __restrict__ h_in,   // [BB][H]
    float*       __restrict__ h_out,  // [BB][H]
    float*       __restrict__ c_st)   // [BB][H] in/out
{
    constexpr int KT  = XK + HID;
    constexpr int NCH = KT / 256;

    __shared__ float Ach[32 * 256];     // 32KB, row-major by b, quad-XOR cols
    __shared__ float Wch[8 * 256];      // 8KB, row-major by r, quad-XOR cols
    __shared__ float part[16 * 8 * 32]; // 16KB split-K partials
    __shared__ float gs[8 * 32];
    __shared__ int   tokl[32];
    __shared__ float pvr[512];
    __shared__ int   pir[512];

    const int tid = threadIdx.x;
    const int bg  = tid & 7;
    const int jg  = (tid >> 3) & 3;
    const int ks  = tid >> 5;
    const int j0  = blockIdx.x * 2;

    // ---- resolve embedding row indices ----
    if (emb) {
        if (pval) {
            const int b = tid & 31, pg = tid >> 5;
            float bv = -3.402823e38f; int bi = 0x7fffffff;
            for (int p = pg; p < NPRT; p += 16) {
                const float v = pval[p * 32 + b];
                const int  ix = pidx[p * 32 + b];
                if (v > bv || (v == bv && ix < bi)) { bv = v; bi = ix; }
            }
            pvr[pg * 32 + b] = bv; pir[pg * 32 + b] = bi;
            __syncthreads();
            if (tid < 32) {
                float v0 = pvr[tid]; int i0 = pir[tid];
                #pragma unroll
                for (int g = 1; g < 16; ++g) {
                    const float v = pvr[g * 32 + tid];
                    const int  ix = pir[g * 32 + tid];
                    if (v > v0 || (v == v0 && ix < i0)) { v0 = v; i0 = ix; }
                }
                tokl[tid] = i0;
            }
            __syncthreads();
        } else if (idx) {
            if (tid < 32) tokl[tid] = idx[tid * idx_stride + idx_off];
            __syncthreads();
        } else {
            if (tid < 32) tokl[tid] = tok[tid];
            __syncthreads();
        }
    }

    // ---- staging coords ----
    const int arow  = tid >> 4;             // act row 0..31
    const int aslot = tid & 15;             // 16 floats each
    const int swzA  = ((arow >> 2) ^ ((arow & 3) << 1)) & 7;
    const int wr    = tid >> 6;             // W block-row 0..7 (wave-uniform)
    const int wl    = tid & 63;             // quad within row
    const int wrow_g = j0 + (wr & 1) + (wr >> 1) * HID;

    const float* arowx;
    if (emb) arowx = emb + (size_t)tokl[arow] * XK;
    else     arowx = xdir + (size_t)arow * XK;
    const float* arowh = h_in + (size_t)arow * HID;

    float4 aR[4]; float4 wR;
    auto LOADCH = [&](int ch) {
        const int kb = ch * 256;
        const float* as = (kb < XK) ? (arowx + kb) : (arowh + (kb - XK));
        const float* ws = (kb < XK) ? (Wih + (size_t)wrow_g * XK + kb)
                                    : (Whh + (size_t)wrow_g * HID + (kb - XK));
        #pragma unroll
        for (int q = 0; q < 4; ++q)
            aR[q] = *reinterpret_cast<const float4*>(as + aslot * 16 + q * 4);
        wR = *reinterpret_cast<const float4*>(ws + wl * 4);
    };
    auto STORECH = [&]() {
        #pragma unroll
        for (int q = 0; q < 4; ++q) {
            const int kq = aslot * 4 + q;
            const int co = ((kq & ~7) | ((kq ^ swzA) & 7)) * 4;
            *reinterpret_cast<float4*>(&Ach[arow * 256 + co]) = aR[q];
        }
        const int wco = ((wl & ~7) | ((wl ^ wr) & 7)) * 4;
        *reinterpret_cast<float4*>(&Wch[wr * 256 + wco]) = wR;
    };

    float acc[2][4];
    #pragma unroll
    for (int p = 0; p < 2; ++p)
        #pragma unroll
        for (int i = 0; i < 4; ++i) acc[p][i] = 0.0f;

    LOADCH(0);
    STORECH();
    __syncthreads();

    for (int ch = 0; ch < NCH; ++ch) {
        const bool more = (ch + 1 < NCH);
        if (more) LOADCH(ch + 1);   // overlaps with compute below

        #pragma unroll
        for (int q = 0; q < 4; ++q) {
            const int kq = ks * 4 + q;
            const int kh = (kq & ~7) * 4;
            float4 av[4];
            #pragma unroll
            for (int i = 0; i < 4; ++i) {
                const int sl = ((kq ^ (bg ^ (i * 2))) & 7) * 4;
                av[i] = *reinterpret_cast<const float4*>(&Ach[(bg * 4 + i) * 256 + kh + sl]);
            }
            #pragma unroll
            for (int p = 0; p < 2; ++p) {
                const int r  = jg * 2 + p;
                const int sl = ((kq ^ r) & 7) * 4;
                const float4 wv = *reinterpret_cast<const float4*>(&Wch[r * 256 + kh + sl]);
                #pragma unroll
                for (int i = 0; i < 4; ++i) acc[p][i] += dot4(av[i], wv);
            }
        }
        __syncthreads();
        if (more) { STORECH(); __syncthreads(); }
    }

    // ---- split-K reduce + pointwise ----
    #pragma unroll
    for (int p = 0; p < 2; ++p)
        #pragma unroll
        for (int i = 0; i < 4; ++i)
            part[(ks * 8 + jg * 2 + p) * 32 + bg * 4 + i] = acc[p][i];
    __syncthreads();

    if (tid < 256) {
        const int r = tid >> 5, b = tid & 31;
        float s = 0.0f;
        #pragma unroll
        for (int k2 = 0; k2 < 16; ++k2) s += part[(k2 * 8 + r) * 32 + b];
        gs[r * 32 + b] = s;
    }
    __syncthreads();

    if (tid < 64) {
        const int jl = tid >> 5, b = tid & 31;
        const int j  = j0 + jl;
        float g4[4];
        #pragma unroll
        for (int g = 0; g < 4; ++g)
            g4[g] = gs[(g * 2 + jl) * 32 + b] + bias[j + g * HID];
        const float cp = c_st[b * HID + j];
        const float cn = sgm(g4[1]) * cp + sgm(g4[0]) * tanhf(g4[2]);
        const float hn = sgm(g4[3]) * tanhf(cn);
        c_st[b * HID + j]  = cn;
        h_out[b * HID + j] = hn;
    }
}

// ---------------------------------------------------------------------------
// Logits + per-block argmax partials. grid = 500 (64 v each), block = 512.
// b = tid&31, vs = tid>>5 (16 groups of 4 v). Pipelined staging like the cell.
// ---------------------------------------------------------------------------
__global__ void __launch_bounds__(512) logits_kernel(
    const float* __restrict__ h1,    // [BB][H]
    const float* __restrict__ W,     // [V][H]
    const float* __restrict__ bias,  // [V]
    float*       __restrict__ out,   // [BB][TDEC][1][V]
    int t,
    float*       __restrict__ pval,  // [500][BB]
    int*         __restrict__ pidx)  // [500][BB]
{
    __shared__ float Wch[64 * 128];  // 32KB
    __shared__ float Ach[32 * 128];  // 16KB
    __shared__ float rv[16 * 32];
    __shared__ int   ri[16 * 32];

    const int tid = threadIdx.x;
    const int b   = tid & 31;
    const int vs  = tid >> 5;        // 0..15
    const int v0  = blockIdx.x * 64;
    const int bsw = (b & 7) << 2;

    const int wro0 = tid >> 5, wco0 = (tid & 31) * 4;       // + 16*i rows
    const int aro  = tid >> 5, aco  = (tid & 31) * 4;       // rows 0..15 (+16)
    const int asw0 = (aro & 7) << 2;

    float4 wR[4]; float4 aR[2];
    auto LOADCH = [&](int ch) {
        const int k0 = ch * 128;
        #pragma unroll
        for (int i = 0; i < 4; ++i)
            wR[i] = *reinterpret_cast<const float4*>(
                W + (size_t)(v0 + wro0 + 16 * i) * HID + k0 + wco0);
        #pragma unroll
        for (int i = 0; i < 2; ++i) {
            const int r  = aro + 16 * i;
            const int sw = (r & 7) << 2;
            aR[i] = *reinterpret_cast<const float4*>(
                h1 + (size_t)r * HID + k0 + (aco ^ sw));
        }
    };
    auto STORECH = [&]() {
        #pragma unroll
        for (int i = 0; i < 4; ++i)
            *reinterpret_cast<float4*>(&Wch[(wro0 + 16 * i) * 128 + wco0]) = wR[i];
        #pragma unroll
        for (int i = 0; i < 2; ++i)
            *reinterpret_cast<float4*>(&Ach[(aro + 16 * i) * 128 + aco]) = aR[i];
    };

    float acc[4] = {0.f, 0.f, 0.f, 0.f};

    LOADCH(0);
    STORECH();
    __syncthreads();

    for (int ch = 0; ch < 8; ++ch) {
        const bool more = (ch + 1 < 8);
        if (more) LOADCH(ch + 1);

        #pragma unroll
        for (int kk = 0; kk < 128; kk += 4) {
            const float4 a = *reinterpret_cast<const float4*>(&Ach[b * 128 + (kk ^ bsw)]);
            #pragma unroll
            for (int i = 0; i < 4; ++i) {
                const float4 w = *reinterpret_cast<const float4*>(&Wch[(vs * 4 + i) * 128 + kk]);
                acc[i] += dot4(a, w);
            }
        }
        __syncthreads();
        if (more) { STORECH(); __syncthreads(); }
    }

    // bias + output + local argmax (ascending v => first-max tie-break)
    const int vbase = v0 + vs * 4;
    float res[4];
    float bestv = -3.402823e38f;
    int   besti = 0;
    #pragma unroll
    for (int i = 0; i < 4; ++i) {
        res[i] = acc[i] + bias[vbase + i];
        if (res[i] > bestv) { bestv = res[i]; besti = vbase + i; }
    }
    const size_t obase = ((size_t)b * TDEC + t) * (size_t)NV + vbase;
    *reinterpret_cast<float4*>(&out[obase]) = make_float4(res[0], res[1], res[2], res[3]);

    rv[vs * 32 + b] = bestv;
    ri[vs * 32 + b] = besti;
    __syncthreads();
    if (vs == 0) {
        float bv = rv[b];
        int   bi = ri[b];
        #pragma unroll
        for (int i = 1; i < 16; ++i) {
            const float v = rv[i * 32 + b];
            const int  ix = ri[i * 32 + b];
            if (v > bv || (v == bv && ix < bi)) { bv = v; bi = ix; }
        }
        pval[(size_t)blockIdx.x * BB + b] = bv;
        pidx[(size_t)blockIdx.x * BB + b] = bi;
    }
}

__global__ void __launch_bounds__(256) init_state(
    float* h0, float* c0, float* h1, float* c1, int* tok)
{
    const int i = blockIdx.x * 256 + threadIdx.x;
    if (i < BB * HID) { h0[i] = 0.f; c0[i] = 0.f; h1[i] = 0.f; c1[i] = 0.f; }
    if (i < BB) tok[i] = 1;  // BOS
}

// ---------------------------------------------------------------------------
extern "C" void kernel_launch(void* const* d_in, const int* in_sizes, int n_in,
                              void* d_out, int out_size, void* d_ws, size_t ws_size,
                              hipStream_t stream)
{
    const int*   x       = (const int*)  d_in[0];
    const float* enc_emb = (const float*)d_in[1];
    const float* dec_emb = (const float*)d_in[2];
    const float* eWih0   = (const float*)d_in[3];
    const float* eWhh0   = (const float*)d_in[4];
    const float* eb0     = (const float*)d_in[5];
    const float* eWih1   = (const float*)d_in[6];
    const float* eWhh1   = (const float*)d_in[7];
    const float* eb1     = (const float*)d_in[8];
    const float* dWih0   = (const float*)d_in[9];
    const float* dWhh0   = (const float*)d_in[10];
    const float* db0     = (const float*)d_in[11];
    const float* dWih1   = (const float*)d_in[12];
    const float* dWhh1   = (const float*)d_in[13];
    const float* db1     = (const float*)d_in[14];
    const float* pW      = (const float*)d_in[15];
    const float* pb      = (const float*)d_in[16];
    float* out = (float*)d_out;

    // workspace layout (floats)
    float* w = (float*)d_ws;
    float* h0buf[2] = { w, w + 32768 };
    float* c0       = w + 65536;
    float* h1buf[2] = { w + 98304, w + 131072 };
    float* c1       = w + 163840;
    int*   tok      = (int*)(w + 196608);
    float* pval     = w + 196608 + 64;
    int*   pidx     = (int*)(w + 196608 + 64 + 16000);

    init_state<<<dim3(128), dim3(256), 0, stream>>>(h0buf[0], c0, h1buf[0], c1, tok);

    int cur0 = 0, cur1 = 0;

    // ---- encoder: 128 steps x 2 layers ----
    for (int t = 0; t < SEQ; ++t) {
        lstm_cell<512><<<dim3(512), dim3(512), 0, stream>>>(
            nullptr, enc_emb, x, SEQ, t, nullptr, nullptr, nullptr,
            eWih0, eWhh0, eb0, h0buf[cur0], h0buf[cur0 ^ 1], c0);
        cur0 ^= 1;
        lstm_cell<1024><<<dim3(512), dim3(512), 0, stream>>>(
            h0buf[cur0], nullptr, nullptr, 0, 0, nullptr, nullptr, nullptr,
            eWih1, eWhh1, eb1, h1buf[cur1], h1buf[cur1 ^ 1], c1);
        cur1 ^= 1;
    }

    // ---- decoder: 64 greedy steps (argmax fused into cell0) ----
    for (int t = 0; t < TDEC; ++t) {
        if (t == 0) {
            lstm_cell<1024><<<dim3(512), dim3(512), 0, stream>>>(
                nullptr, dec_emb, nullptr, 0, 0, tok, nullptr, nullptr,
                dWih0, dWhh0, db0, h0buf[cur0], h0buf[cur0 ^ 1], c0);
        } else {
            lstm_cell<1024><<<dim3(512), dim3(512), 0, stream>>>(
                nullptr, dec_emb, nullptr, 0, 0, nullptr, pval, pidx,
                dWih0, dWhh0, db0, h0buf[cur0], h0buf[cur0 ^ 1], c0);
        }
        cur0 ^= 1;
        lstm_cell<1024><<<dim3(512), dim3(512), 0, stream>>>(
            h0buf[cur0], nullptr, nullptr, 0, 0, nullptr, nullptr, nullptr,
            dWih1, dWhh1, db1, h1buf[cur1], h1buf[cur1 ^ 1], c1);
        cur1 ^= 1;
        logits_kernel<<<dim3(500), dim3(512), 0, stream>>>(
            h1buf[cur1], pW, pb, out, t, pval, pidx);
    }
}

// Round 6
// 23172.093 us; speedup vs baseline: 4.7334x; 4.7334x over previous
//
#include <hip/hip_runtime.h>
#include <math.h>

// EncoderDecoder LSTM seq2seq, f32 throughout.
// v4b: v4 with the nontemporal-store compile fix (ext_vector_type instead of
// HIP float4 class). v2's proven no-spill staging skeleton
// (load->bar->store->bar->compute, loads consumed immediately). Compute tiles
// enlarged to cut LDS reads/FMA: cell 4b x 4r (16 acc, 8 FMA/read),
// logits 2b x 4v (5.3 FMA/read). Nontemporal logit stores keep pred_W
// LLC-resident.

#define BB   32
#define SEQ  128
#define HID  1024
#define NV   32000
#define TDEC 64
#define NPRT 250

typedef float f32x4_t __attribute__((ext_vector_type(4)));

__device__ __forceinline__ float sgm(float x) { return 1.0f / (1.0f + expf(-x)); }
__device__ __forceinline__ float dot4(float4 a, float4 b) {
    return a.x*b.x + a.y*b.y + a.z*b.z + a.w*b.w;
}

// ---------------------------------------------------------------------------
// Fused LSTM cell. grid = 512 blocks (2 hidden cols -> 8 gate-rows), block 512.
// tid bits: [0:2]=bq (4 b's = bq*4+i), [3]=rh (4 rows = rh*4+p), [4:8]=ks
// (32-way K split, 8 k = 2 quads per 256-chunk).
// A in LDS: element k of row b at Ach[b*256 + (k ^ ((b&7)*4))] (global side
// pre-swizzled). W in LDS: quad wl of row r at Wch[r*256 + 4*((wl&~7)|((wl^r)&7))].
// ---------------------------------------------------------------------------
template <int XK>
__global__ void __launch_bounds__(512) lstm_cell(
    const float* __restrict__ xdir,   // [BB][XK] or nullptr
    const float* __restrict__ emb,    // [V][XK] or nullptr
    const int*   __restrict__ idx, int idx_stride, int idx_off,
    const int*   __restrict__ tok,    // decoder t=0 token path
    const float* __restrict__ pval,   // fused-argmax path (decoder t>0)
    const int*   __restrict__ pidx,
    const float* __restrict__ Wih,    // [4H][XK]
    const float* __restrict__ Whh,    // [4H][H]
    const float* __restrict__ bias,   // [4H]
    const float* __restrict__ h_in,   // [BB][H]
    float*       __restrict__ h_out,  // [BB][H]
    float*       __restrict__ c_st)   // [BB][H] in/out
{
    constexpr int KT  = XK + HID;
    constexpr int NCH = KT / 256;

    __shared__ float Ach[32 * 256];     // 32KB
    __shared__ float Wch[8 * 256];      // 8KB
    __shared__ float part[32 * 8 * 32]; // 32KB split-K partials
    __shared__ float gs[8 * 32];
    __shared__ int   tokl[32];
    __shared__ float pvr[512];
    __shared__ int   pir[512];

    const int tid = threadIdx.x;
    const int bq  = tid & 7;
    const int rh  = (tid >> 3) & 1;
    const int ks  = tid >> 4;
    const int j0  = blockIdx.x * 2;

    // ---- resolve embedding row indices ----
    if (emb) {
        if (pval) {
            const int b = tid & 31, pg = tid >> 5;
            float bv = -3.402823e38f; int bi = 0x7fffffff;
            for (int p = pg; p < NPRT; p += 16) {
                const float v = pval[p * 32 + b];
                const int  ix = pidx[p * 32 + b];
                if (v > bv || (v == bv && ix < bi)) { bv = v; bi = ix; }
            }
            pvr[pg * 32 + b] = bv; pir[pg * 32 + b] = bi;
            __syncthreads();
            if (tid < 32) {
                float v0 = pvr[tid]; int i0 = pir[tid];
                #pragma unroll
                for (int g = 1; g < 16; ++g) {
                    const float v = pvr[g * 32 + tid];
                    const int  ix = pir[g * 32 + tid];
                    if (v > v0 || (v == v0 && ix < i0)) { v0 = v; i0 = ix; }
                }
                tokl[tid] = i0;
            }
            __syncthreads();
        } else if (idx) {
            if (tid < 32) tokl[tid] = idx[tid * idx_stride + idx_off];
            __syncthreads();
        } else {
            if (tid < 32) tokl[tid] = tok[tid];
            __syncthreads();
        }
    }

    // ---- staging coords ----
    const int arow = tid >> 4;            // act row 0..31
    const int al   = tid & 15;            // 4 float4 slots: al*4 + 64*q floats
    const int asw  = (arow & 7) << 2;     // global-side pre-swizzle (floats)
    const int wr   = tid >> 6;            // W row 0..7 (wave-uniform)
    const int wl   = tid & 63;            // quad index in row
    const int wrow_g = j0 + (wr & 1) + (wr >> 1) * HID;
    const int wco  = 4 * ((wl & ~7) | ((wl ^ wr) & 7));

    const float* arowx;
    if (emb) arowx = emb + (size_t)tokl[arow] * XK;
    else     arowx = xdir + (size_t)arow * XK;
    const float* arowh = h_in + (size_t)arow * HID;

    float acc[4][4];
    #pragma unroll
    for (int p = 0; p < 4; ++p)
        #pragma unroll
        for (int i = 0; i < 4; ++i) acc[p][i] = 0.0f;

    for (int ch = 0; ch < NCH; ++ch) {
        const int kb = ch * 256;   // chunk never straddles the XK boundary

        const float* as = (kb < XK) ? (arowx + kb) : (arowh + (kb - XK));
        const float4 a0 = *reinterpret_cast<const float4*>(as + ((al * 4      ) ^ asw));
        const float4 a1 = *reinterpret_cast<const float4*>(as + ((al * 4 +  64) ^ asw));
        const float4 a2 = *reinterpret_cast<const float4*>(as + ((al * 4 + 128) ^ asw));
        const float4 a3 = *reinterpret_cast<const float4*>(as + ((al * 4 + 192) ^ asw));
        const float* ws = (kb < XK) ? (Wih + (size_t)wrow_g * XK + kb)
                                    : (Whh + (size_t)wrow_g * HID + (kb - XK));
        const float4 wv0 = *reinterpret_cast<const float4*>(ws + wl * 4);

        __syncthreads();   // previous chunk's readers done
        *reinterpret_cast<float4*>(&Ach[arow * 256 + al * 4      ]) = a0;
        *reinterpret_cast<float4*>(&Ach[arow * 256 + al * 4 +  64]) = a1;
        *reinterpret_cast<float4*>(&Ach[arow * 256 + al * 4 + 128]) = a2;
        *reinterpret_cast<float4*>(&Ach[arow * 256 + al * 4 + 192]) = a3;
        *reinterpret_cast<float4*>(&Wch[wr * 256 + wco]) = wv0;
        __syncthreads();

        #pragma unroll
        for (int q = 0; q < 2; ++q) {
            const int kq = ks * 2 + q;
            float4 av[4], wf[4];
            #pragma unroll
            for (int i = 0; i < 4; ++i) {
                const int brow = bq * 4 + i;
                av[i] = *reinterpret_cast<const float4*>(
                    &Ach[brow * 256 + 4 * (kq ^ (brow & 7))]);
            }
            #pragma unroll
            for (int p = 0; p < 4; ++p) {
                const int r = rh * 4 + p;
                wf[p] = *reinterpret_cast<const float4*>(
                    &Wch[r * 256 + 4 * ((kq & ~7) | ((kq ^ r) & 7))]);
            }
            #pragma unroll
            for (int p = 0; p < 4; ++p)
                #pragma unroll
                for (int i = 0; i < 4; ++i) acc[p][i] += dot4(av[i], wf[p]);
        }
    }

    // ---- split-K partials ----
    #pragma unroll
    for (int p = 0; p < 4; ++p)
        #pragma unroll
        for (int i = 0; i < 4; ++i)
            part[(ks * 8 + rh * 4 + p) * 32 + bq * 4 + i] = acc[p][i];
    __syncthreads();

    if (tid < 256) {
        const int r = tid >> 5, b = tid & 31;
        float s = 0.0f;
        #pragma unroll
        for (int k2 = 0; k2 < 32; ++k2) s += part[(k2 * 8 + r) * 32 + b];
        gs[r * 32 + b] = s;
    }
    __syncthreads();

    if (tid < 64) {
        const int jl = tid >> 5, b = tid & 31;
        const int j  = j0 + jl;
        float g4[4];
        #pragma unroll
        for (int g = 0; g < 4; ++g)
            g4[g] = gs[(g * 2 + jl) * 32 + b] + bias[j + g * HID];
        const float cp = c_st[b * HID + j];
        const float cn = sgm(g4[1]) * cp + sgm(g4[0]) * tanhf(g4[2]);
        const float hn = sgm(g4[3]) * tanhf(cn);
        c_st[b * HID + j]  = cn;
        h_out[b * HID + j] = hn;
    }
}

// ---------------------------------------------------------------------------
// Logits + per-block argmax partials. grid = 250 (128 v each), block = 512.
// tid bits: [0:3]=bq (2 b's = bq*2+j), [4:8]=vg (4 v = vg*4+i). Full-K per
// thread (no split). Per 128-chunk: 32 quads x (2a + 4w reads, 8 dot4).
// ---------------------------------------------------------------------------
__global__ void __launch_bounds__(512) logits_kernel(
    const float* __restrict__ h1,    // [BB][H]
    const float* __restrict__ W,     // [V][H]
    const float* __restrict__ bias,  // [V]
    float*       __restrict__ out,   // [BB][TDEC][1][V]
    int t,
    float*       __restrict__ pval,  // [250][BB]
    int*         __restrict__ pidx)  // [250][BB]
{
    __shared__ float Wch[128 * 128]; // 64KB, linear
    __shared__ float Ach[32 * 128];  // 16KB, swizzled like the cell
    __shared__ float rv[32 * 32];
    __shared__ int   ri[32 * 32];

    const int tid = threadIdx.x;
    const int bq  = tid & 15;
    const int vg  = tid >> 4;        // 0..31
    const int v0  = blockIdx.x * 128;

    // staging coords
    const int sro = tid >> 5;        // row slice base
    const int scq = tid & 31;        // quad in row

    float acc[2][4];
    #pragma unroll
    for (int j = 0; j < 2; ++j)
        #pragma unroll
        for (int i = 0; i < 4; ++i) acc[j][i] = 0.0f;

    for (int ch = 0; ch < 8; ++ch) {
        const int k0 = ch * 128;

        float4 wR[8];
        #pragma unroll
        for (int i = 0; i < 8; ++i) {
            const int row = sro + 16 * i;   // 0..127
            wR[i] = *reinterpret_cast<const float4*>(
                W + (size_t)(v0 + row) * HID + k0 + scq * 4);
        }
        float4 aR[2];
        #pragma unroll
        for (int i = 0; i < 2; ++i) {
            const int row = sro + 16 * i;   // 0..31
            const int sw  = (row & 7) << 2;
            aR[i] = *reinterpret_cast<const float4*>(
                h1 + (size_t)row * HID + k0 + ((scq * 4) ^ sw));
        }

        __syncthreads();
        #pragma unroll
        for (int i = 0; i < 8; ++i)
            *reinterpret_cast<float4*>(&Wch[(sro + 16 * i) * 128 + scq * 4]) = wR[i];
        #pragma unroll
        for (int i = 0; i < 2; ++i)
            *reinterpret_cast<float4*>(&Ach[(sro + 16 * i) * 128 + scq * 4]) = aR[i];
        __syncthreads();

        #pragma unroll
        for (int kq = 0; kq < 32; ++kq) {
            const int b0 = bq * 2, b1 = bq * 2 + 1;
            const float4 a0 = *reinterpret_cast<const float4*>(
                &Ach[b0 * 128 + 4 * (kq ^ (b0 & 7))]);
            const float4 a1 = *reinterpret_cast<const float4*>(
                &Ach[b1 * 128 + 4 * (kq ^ (b1 & 7))]);
            #pragma unroll
            for (int i = 0; i < 4; ++i) {
                const float4 wf = *reinterpret_cast<const float4*>(
                    &Wch[(vg * 4 + i) * 128 + kq * 4]);
                acc[0][i] += dot4(a0, wf);
                acc[1][i] += dot4(a1, wf);
            }
        }
    }

    // bias + nontemporal output + per-thread argmax (ascending i tie-break)
    const int vbase = v0 + vg * 4;
    #pragma unroll
    for (int j = 0; j < 2; ++j) {
        const int b = bq * 2 + j;
        float res[4];
        float bestv = -3.402823e38f;
        int   besti = 0;
        #pragma unroll
        for (int i = 0; i < 4; ++i) {
            res[i] = acc[j][i] + bias[vbase + i];
            if (res[i] > bestv) { bestv = res[i]; besti = vbase + i; }
        }
        const size_t ob = ((size_t)b * TDEC + t) * (size_t)NV + vbase;
        f32x4_t nt_v;
        nt_v.x = res[0]; nt_v.y = res[1]; nt_v.z = res[2]; nt_v.w = res[3];
        __builtin_nontemporal_store(nt_v, reinterpret_cast<f32x4_t*>(&out[ob]));
        rv[vg * 32 + b] = bestv;
        ri[vg * 32 + b] = besti;
    }
    __syncthreads();
    if (tid < 32) {
        const int b = tid;
        float bv = rv[b];
        int   bi = ri[b];
        #pragma unroll
        for (int g = 1; g < 32; ++g) {
            const float v = rv[g * 32 + b];
            const int  ix = ri[g * 32 + b];
            if (v > bv || (v == bv && ix < bi)) { bv = v; bi = ix; }
        }
        pval[(size_t)blockIdx.x * BB + b] = bv;
        pidx[(size_t)blockIdx.x * BB + b] = bi;
    }
}

__global__ void __launch_bounds__(256) init_state(
    float* h0, float* c0, float* h1, float* c1, int* tok)
{
    const int i = blockIdx.x * 256 + threadIdx.x;
    if (i < BB * HID) { h0[i] = 0.f; c0[i] = 0.f; h1[i] = 0.f; c1[i] = 0.f; }
    if (i < BB) tok[i] = 1;  // BOS
}

// ---------------------------------------------------------------------------
extern "C" void kernel_launch(void* const* d_in, const int* in_sizes, int n_in,
                              void* d_out, int out_size, void* d_ws, size_t ws_size,
                              hipStream_t stream)
{
    const int*   x       = (const int*)  d_in[0];
    const float* enc_emb = (const float*)d_in[1];
    const float* dec_emb = (const float*)d_in[2];
    const float* eWih0   = (const float*)d_in[3];
    const float* eWhh0   = (const float*)d_in[4];
    const float* eb0     = (const float*)d_in[5];
    const float* eWih1   = (const float*)d_in[6];
    const float* eWhh1   = (const float*)d_in[7];
    const float* eb1     = (const float*)d_in[8];
    const float* dWih0   = (const float*)d_in[9];
    const float* dWhh0   = (const float*)d_in[10];
    const float* db0     = (const float*)d_in[11];
    const float* dWih1   = (const float*)d_in[12];
    const float* dWhh1   = (const float*)d_in[13];
    const float* db1     = (const float*)d_in[14];
    const float* pW      = (const float*)d_in[15];
    const float* pb      = (const float*)d_in[16];
    float* out = (float*)d_out;

    // workspace layout (floats)
    float* w = (float*)d_ws;
    float* h0buf[2] = { w, w + 32768 };
    float* c0       = w + 65536;
    float* h1buf[2] = { w + 98304, w + 131072 };
    float* c1       = w + 163840;
    int*   tok      = (int*)(w + 196608);
    float* pval     = w + 196608 + 64;
    int*   pidx     = (int*)(w + 196608 + 64 + 8000);

    init_state<<<dim3(128), dim3(256), 0, stream>>>(h0buf[0], c0, h1buf[0], c1, tok);

    int cur0 = 0, cur1 = 0;

    // ---- encoder: 128 steps x 2 layers ----
    for (int t = 0; t < SEQ; ++t) {
        lstm_cell<512><<<dim3(512), dim3(512), 0, stream>>>(
            nullptr, enc_emb, x, SEQ, t, nullptr, nullptr, nullptr,
            eWih0, eWhh0, eb0, h0buf[cur0], h0buf[cur0 ^ 1], c0);
        cur0 ^= 1;
        lstm_cell<1024><<<dim3(512), dim3(512), 0, stream>>>(
            h0buf[cur0], nullptr, nullptr, 0, 0, nullptr, nullptr, nullptr,
            eWih1, eWhh1, eb1, h1buf[cur1], h1buf[cur1 ^ 1], c1);
        cur1 ^= 1;
    }

    // ---- decoder: 64 greedy steps (argmax fused into cell0) ----
    for (int t = 0; t < TDEC; ++t) {
        if (t == 0) {
            lstm_cell<1024><<<dim3(512), dim3(512), 0, stream>>>(
                nullptr, dec_emb, nullptr, 0, 0, tok, nullptr, nullptr,
                dWih0, dWhh0, db0, h0buf[cur0], h0buf[cur0 ^ 1], c0);
        } else {
            lstm_cell<1024><<<dim3(512), dim3(512), 0, stream>>>(
                nullptr, dec_emb, nullptr, 0, 0, nullptr, pval, pidx,
                dWih0, dWhh0, db0, h0buf[cur0], h0buf[cur0 ^ 1], c0);
        }
        cur0 ^= 1;
        lstm_cell<1024><<<dim3(512), dim3(512), 0, stream>>>(
            h0buf[cur0], nullptr, nullptr, 0, 0, nullptr, nullptr, nullptr,
            dWih1, dWhh1, db1, h1buf[cur1], h1buf[cur1 ^ 1], c1);
        cur1 ^= 1;
        logits_kernel<<<dim3(250), dim3(512), 0, stream>>>(
            h1buf[cur1], pW, pb, out, t, pval, pidx);
    }
}